// Round 3
// baseline (34.449 us; speedup 1.0000x reference)
//
#include <hip/hip_runtime.h>

// Householder reflection: out = z - 2 * v * (v.z) / (v.v), row-wise.
// B = 16384 rows, L = 1024 cols, fp32.
//
// One 64-lane wave per TWO consecutive rows, fully unrolled:
//  - 16 float4 loads issued back-to-back (256 B/lane in flight)
//  - two independent shuffle-reduce chains interleave (half the lgkm bubble)
//  - stores of both rows issue after their own reduce only.
// This targets the latency bubble (load-drain -> serial reduce -> store)
// that held the single-row version to ~4 TB/s effective.

typedef float fvec4 __attribute__((ext_vector_type(4)));

constexpr int L = 1024;
constexpr int F4_PER_ROW = L / 4;        // 256 float4 per row
constexpr int ROWS_PER_WAVE = 2;
constexpr int WAVES_PER_BLOCK = 4;
constexpr int THREADS = WAVES_PER_BLOCK * 64;

__global__ __launch_bounds__(THREADS) void householder_kernel(
    const fvec4* __restrict__ v4, const fvec4* __restrict__ z4,
    fvec4* __restrict__ o4, int B) {
  const int lane = threadIdx.x & 63;
  const int gwave = (blockIdx.x * THREADS + (int)threadIdx.x) >> 6;
  const int row0 = gwave * ROWS_PER_WAVE;
  if (row0 >= B) return;

  fvec4 va[ROWS_PER_WAVE][4], za[ROWS_PER_WAVE][4];

  // Issue ALL loads first — 16 dwordx4 per lane in flight.
#pragma unroll
  for (int r = 0; r < ROWS_PER_WAVE; ++r) {
    const fvec4* __restrict__ vr = v4 + (size_t)(row0 + r) * F4_PER_ROW;
    const fvec4* __restrict__ zr = z4 + (size_t)(row0 + r) * F4_PER_ROW;
#pragma unroll
    for (int k = 0; k < 4; ++k) {
      va[r][k] = vr[k * 64 + lane];
      za[r][k] = zr[k * 64 + lane];
    }
  }

  float vz[ROWS_PER_WAVE], vv[ROWS_PER_WAVE];
#pragma unroll
  for (int r = 0; r < ROWS_PER_WAVE; ++r) {
    vz[r] = 0.0f;
    vv[r] = 0.0f;
#pragma unroll
    for (int k = 0; k < 4; ++k) {
      vz[r] += va[r][k].x * za[r][k].x + va[r][k].y * za[r][k].y +
               va[r][k].z * za[r][k].z + va[r][k].w * za[r][k].w;
      vv[r] += va[r][k].x * va[r][k].x + va[r][k].y * va[r][k].y +
               va[r][k].z * va[r][k].z + va[r][k].w * va[r][k].w;
    }
  }

  // Two independent butterfly chains — interleaved by the scheduler,
  // so the per-step shuffle latency is ~half hidden.
#pragma unroll
  for (int off = 32; off >= 1; off >>= 1) {
#pragma unroll
    for (int r = 0; r < ROWS_PER_WAVE; ++r) {
      vz[r] += __shfl_xor(vz[r], off, 64);
      vv[r] += __shfl_xor(vv[r], off, 64);
    }
  }

#pragma unroll
  for (int r = 0; r < ROWS_PER_WAVE; ++r) {
    const float s = -2.0f * vz[r] / vv[r];
    fvec4* __restrict__ orow = o4 + (size_t)(row0 + r) * F4_PER_ROW;
#pragma unroll
    for (int k = 0; k < 4; ++k) {
      fvec4 o;
      o.x = fmaf(s, va[r][k].x, za[r][k].x);
      o.y = fmaf(s, va[r][k].y, za[r][k].y);
      o.z = fmaf(s, va[r][k].z, za[r][k].z);
      o.w = fmaf(s, va[r][k].w, za[r][k].w);
      __builtin_nontemporal_store(o, &orow[k * 64 + lane]);
    }
  }
}

extern "C" void kernel_launch(void* const* d_in, const int* in_sizes, int n_in,
                              void* d_out, int out_size, void* d_ws, size_t ws_size,
                              hipStream_t stream) {
  const fvec4* v = (const fvec4*)d_in[0];
  const fvec4* z = (const fvec4*)d_in[1];
  fvec4* out = (fvec4*)d_out;
  const int B = in_sizes[0] / L;  // 16384
  const int rows_per_block = WAVES_PER_BLOCK * ROWS_PER_WAVE;
  const int grid = (B + rows_per_block - 1) / rows_per_block;
  householder_kernel<<<grid, THREADS, 0, stream>>>(v, z, out, B);
}